// Round 7
// baseline (317.557 us; speedup 1.0000x reference)
//
#include <hip/hip_runtime.h>
#include <hip/hip_bf16.h>
#include <math.h>

// GAT encoder, round 7.  9 dispatches:
//  memset | prep_all (split W1,W2 + dst hist) | scan_ab | scan_c | fill |
//  gemm1 (fp32-A in-kernel split, 128x256 tile = both heads, alpha1 fused) |
//  agg1 | gemm2 | agg2.

#define NSLOPE 0.2f

using bf16x8 = __attribute__((ext_vector_type(8))) short;
using f32x4  = __attribute__((ext_vector_type(4))) float;
using u16x8  = __attribute__((ext_vector_type(8))) unsigned short;
using u16x4  = __attribute__((ext_vector_type(4))) unsigned short;

__device__ __forceinline__ unsigned short bf16_rne(float f) {
    unsigned u = __float_as_uint(f);
    return (unsigned short)((u + 0x7FFFu + ((u >> 16) & 1u)) >> 16);
}
__device__ __forceinline__ float bf16_to_f(unsigned short h) {
    return __uint_as_float(((unsigned)h) << 16);
}

// ---------------- merged prep: prepW1 | prepW2 | hist ----------------
__global__ __launch_bounds__(256) void k_prep_all(const float* __restrict__ W1,
                                                  const float* __restrict__ W2,
                                                  const int* __restrict__ edst,
                                                  unsigned short* __restrict__ W1hi,
                                                  unsigned short* __restrict__ W1lo,
                                                  unsigned short* __restrict__ W2hi,
                                                  unsigned short* __restrict__ W2lo,
                                                  int* __restrict__ deg, int E) {
    int b = blockIdx.x, t = threadIdx.x;
    if (b < 64) {  // split+transpose W1 [256,256] -> [n][k]
        int id = b * 256 + t;
        int n = id >> 6, kg = id & 63;
        unsigned short hi[4], lo[4];
#pragma unroll
        for (int c = 0; c < 4; ++c) {
            float w = W1[(kg * 4 + c) * 256 + n];
            unsigned short h = bf16_rne(w);
            hi[c] = h;
            lo[c] = bf16_rne(w - bf16_to_f(h));
        }
        *(u16x4*)&W1hi[n * 256 + kg * 4] = *(u16x4*)hi;
        *(u16x4*)&W1lo[n * 256 + kg * 4] = *(u16x4*)lo;
    } else if (b < 128) {  // split+transpose W2 [256,64] -> [n][k]
        int id = (b - 64) * 256 + t;
        int n = id >> 8, k = id & 255;
        float w = W2[k * 64 + n];
        unsigned short h = bf16_rne(w);
        W2hi[n * 256 + k] = h;
        W2lo[n * 256 + k] = bf16_rne(w - bf16_to_f(h));
    } else {  // dst-degree histogram
        int i = (b - 128) * 256 + t;
        if (i < E) atomicAdd(&deg[edst[i]], 1);
    }
}

// -------- fused scan: per-block sums + last-block scans the 256 partials -----
__global__ __launch_bounds__(256) void k_scan_ab(const int* __restrict__ deg,
                                                 int* __restrict__ part,
                                                 int* __restrict__ ticket,
                                                 int* __restrict__ off_n,
                                                 int n, int CH) {
    __shared__ int sd[256];
    __shared__ int lastflag;
    int b = blockIdx.x, t = threadIdx.x;
    int s = b * CH, e = min(n, s + CH);
    int loc = 0;
    for (int i = s + t; i < e; i += 256) loc += deg[i] + 1;  // +1 self-loop
    sd[t] = loc;
    __syncthreads();
    for (int o = 128; o > 0; o >>= 1) {
        if (t < o) sd[t] += sd[t + o];
        __syncthreads();
    }
    if (t == 0) {
        part[b] = sd[0];
        __threadfence();
        int old = atomicAdd(ticket, 1);
        lastflag = (old == (int)gridDim.x - 1);
    }
    __syncthreads();
    if (lastflag) {
        __threadfence();
        int v = ((volatile int*)part)[t];
        sd[t] = v;
        __syncthreads();
        for (int o = 1; o < 256; o <<= 1) {
            int u = (t >= o) ? sd[t - o] : 0;
            __syncthreads();
            sd[t] += u;
            __syncthreads();
        }
        part[t] = sd[t] - v;  // exclusive base per block
        if (t == 255) *off_n = sd[255];
    }
}

__global__ __launch_bounds__(256) void k_scan_c(const int* __restrict__ deg,
                                                const int* __restrict__ part,
                                                int* __restrict__ off,
                                                int* __restrict__ cur,
                                                int* __restrict__ srcl, int n, int CH) {
    __shared__ int sd[256];
    int b = blockIdx.x, t = threadIdx.x;
    int s = b * CH, e = min(n, s + CH);
    int base = part[b];
    for (int c = s; c < e; c += 256) {
        int i = c + t;
        int v = (i < e) ? (deg[i] + 1) : 0;
        sd[t] = v;
        __syncthreads();
        for (int o = 1; o < 256; o <<= 1) {
            int u = (t >= o) ? sd[t - o] : 0;
            __syncthreads();
            sd[t] += u;
            __syncthreads();
        }
        if (i < e) {
            int ex = base + sd[t] - v;
            off[i] = ex;
            cur[i] = ex + 1;   // slot ex holds the self-loop
            srcl[ex] = i;
        }
        base += sd[255];
        __syncthreads();
    }
}

__global__ void k_fill(const int* __restrict__ src, const int* __restrict__ dst,
                       int* cur, int* __restrict__ srcl, int E) {
    int i = blockIdx.x * blockDim.x + threadIdx.x;
    if (i >= E) return;
    int s = src[i], d = dst[i];
    int p = atomicAdd(&cur[d], 1);
    srcl[p] = s;
}

// ------ GEMM1: fp32-A (in-kernel hi/lo split), 128x256 tile, alpha1 fused ----
// 4 waves in 2x2: wave = (rhalf, head). Each wave: 64 rows x 128 cols (one head).
#define G1S 40  // LDS row stride in ushort (32 k + 8 pad)
__global__ __launch_bounds__(256) void k_gemm1(const float* __restrict__ x,
                                               const unsigned short* __restrict__ Whi,
                                               const unsigned short* __restrict__ Wlo,
                                               const float* __restrict__ a1s,
                                               const float* __restrict__ a1d,
                                               unsigned short* __restrict__ h1b,
                                               float* __restrict__ as_,
                                               float* __restrict__ ad_, int M) {
    __shared__ unsigned short sAh[128 * G1S], sAl[128 * G1S];
    __shared__ unsigned short sBh[256 * G1S], sBl[256 * G1S];
    int t = threadIdx.x;
    int lane = t & 63, wave = t >> 6;
    int q = lane >> 4, m = lane & 15;
    int row0 = blockIdx.x * 128;
    int rbase = (wave & 1) * 64;
    int head = wave >> 1;
    int cb = head * 128;           // B-row base for this wave
    f32x4 acc[4][8];
#pragma unroll
    for (int i = 0; i < 4; ++i)
#pragma unroll
        for (int j = 0; j < 8; ++j) acc[i][j] = (f32x4){0.f, 0.f, 0.f, 0.f};

    for (int kc = 0; kc < 256; kc += 32) {
        // stage A: 128 rows x 32 k from fp32 x, split to hi/lo
#pragma unroll
        for (int i2 = 0; i2 < 4; ++i2) {
            int slot = t + i2 * 256;           // 0..1023
            int r = slot >> 3, kg = slot & 7;  // r:0..127, kg:0..7 (float4s)
            int row = row0 + r;
            float4 v = make_float4(0.f, 0.f, 0.f, 0.f);
            if (row < M) v = *(const float4*)&x[(size_t)row * 256 + kc + kg * 4];
            float vv[4] = {v.x, v.y, v.z, v.w};
            unsigned short hi[4], lo[4];
#pragma unroll
            for (int c = 0; c < 4; ++c) {
                unsigned short h = bf16_rne(vv[c]);
                hi[c] = h;
                lo[c] = bf16_rne(vv[c] - bf16_to_f(h));
            }
            *(u16x4*)&sAh[r * G1S + kg * 4] = *(u16x4*)hi;
            *(u16x4*)&sAl[r * G1S + kg * 4] = *(u16x4*)lo;
        }
        // stage B: 256 cols(n) x 32 k (hi+lo), pre-transposed W [n][k]
#pragma unroll
        for (int i2 = 0; i2 < 4; ++i2) {
            int slot = t + i2 * 256;            // 0..1023
            int n = slot >> 2, kg = slot & 3;   // n:0..255, kg:0..3 (u16x8s)
            *(u16x8*)&sBh[n * G1S + kg * 8] =
                *(const u16x8*)&Whi[(size_t)n * 256 + kc + kg * 8];
            *(u16x8*)&sBl[n * G1S + kg * 8] =
                *(const u16x8*)&Wlo[(size_t)n * 256 + kc + kg * 8];
        }
        __syncthreads();
        bf16x8 ah[4], al[4];
#pragma unroll
        for (int i = 0; i < 4; ++i) {
            int r = (rbase + i * 16 + m) * G1S + q * 8;
            ah[i] = *(bf16x8*)&sAh[r];
            al[i] = *(bf16x8*)&sAl[r];
        }
#pragma unroll
        for (int j = 0; j < 8; ++j) {
            int rB = (cb + j * 16 + m) * G1S + q * 8;
            bf16x8 bhj = *(bf16x8*)&sBh[rB];
            bf16x8 blj = *(bf16x8*)&sBl[rB];
#pragma unroll
            for (int i = 0; i < 4; ++i) {
                acc[i][j] = __builtin_amdgcn_mfma_f32_16x16x32_bf16(ah[i], blj, acc[i][j], 0, 0, 0);
                acc[i][j] = __builtin_amdgcn_mfma_f32_16x16x32_bf16(al[i], bhj, acc[i][j], 0, 0, 0);
                acc[i][j] = __builtin_amdgcn_mfma_f32_16x16x32_bf16(ah[i], bhj, acc[i][j], 0, 0, 0);
            }
        }
        __syncthreads();
    }
    // epilogue: each wave owns 64 rows x 128 cols = one full head -> direct alpha
    float sv[8], dv[8];
#pragma unroll
    for (int j = 0; j < 8; ++j) {
        sv[j] = a1s[head * 128 + j * 16 + m];
        dv[j] = a1d[head * 128 + j * 16 + m];
    }
#pragma unroll
    for (int i = 0; i < 4; ++i) {
#pragma unroll
        for (int r = 0; r < 4; ++r) {
            int row = row0 + rbase + i * 16 + q * 4 + r;
            float ps = 0.f, pd = 0.f;
#pragma unroll
            for (int j = 0; j < 8; ++j) {
                ps += acc[i][j][r] * sv[j];
                pd += acc[i][j][r] * dv[j];
            }
#pragma unroll
            for (int mask = 1; mask < 16; mask <<= 1) {
                ps += __shfl_xor(ps, mask, 64);
                pd += __shfl_xor(pd, mask, 64);
            }
            if (row < M) {
#pragma unroll
                for (int j = 0; j < 8; ++j)
                    h1b[(size_t)row * 256 + head * 128 + j * 16 + m] = bf16_rne(acc[i][j][r]);
                if (m == 0) {
                    as_[row * 2 + head] = ps;
                    ad_[row * 2 + head] = pd;
                }
            }
        }
    }
}

// ------- layer-1 aggregate: inline softmax-w, half-wave/edge, 2-in-flight ----
__global__ __launch_bounds__(256) void k_agg1(const unsigned short* __restrict__ h1b,
                                              const float* __restrict__ as,
                                              const float* __restrict__ ad,
                                              const int* __restrict__ off,
                                              const int* __restrict__ srcl,
                                              const float* __restrict__ b1,
                                              unsigned short* __restrict__ helu_b, int N) {
    int wid = (blockIdx.x * blockDim.x + threadIdx.x) >> 6;
    int lane = threadIdx.x & 63;
    if (wid >= N) return;
    int p0 = off[wid], p1 = off[wid + 1];
    float ad0 = ad[wid * 2], ad1 = ad[wid * 2 + 1];
    int half = lane >> 5, hl = lane & 31;
    int headL = hl >> 4;
    float acc[8];
#pragma unroll
    for (int c = 0; c < 8; ++c) acc[c] = 0.f;
    float sumw = 0.f;
    for (int base = p0; base < p1; base += 64) {
        int p = base + lane;
        int cnt = min(64, p1 - base);
        int s = 0; float w0 = 0.f, w1 = 0.f;
        if (p < p1) {
            s = srcl[p];
            float2 av = *(const float2*)&as[s * 2];
            float l0 = av.x + ad0; l0 = l0 >= 0.f ? l0 : NSLOPE * l0;
            float l1 = av.y + ad1; l1 = l1 >= 0.f ? l1 : NSLOPE * l1;
            w0 = __expf(l0); w1 = __expf(l1);
        }
        int pairs = (cnt + 1) >> 1;
        int jj = 0;
        for (; jj + 2 <= pairs; jj += 2) {
            int e0 = 2 * jj + half, e1 = e0 + 2;
            int sa = __shfl(s, e0, 64), sb = __shfl(s, e1, 64);
            float wa0 = __shfl(w0, e0, 64), wa1 = __shfl(w1, e0, 64);
            float wb0 = __shfl(w0, e1, 64), wb1 = __shfl(w1, e1, 64);
            u16x8 hva = *(const u16x8*)&h1b[(size_t)sa * 256 + hl * 8];
            u16x8 hvb = *(const u16x8*)&h1b[(size_t)sb * 256 + hl * 8];
            float wa = headL ? wa1 : wa0;
            float wb = headL ? wb1 : wb0;
            sumw += wa + wb;
#pragma unroll
            for (int c = 0; c < 8; ++c)
                acc[c] += wa * bf16_to_f(hva[c]) + wb * bf16_to_f(hvb[c]);
        }
        for (; jj < pairs; ++jj) {
            int e0 = 2 * jj + half;
            int sa = __shfl(s, e0, 64);
            float wa0 = __shfl(w0, e0, 64), wa1 = __shfl(w1, e0, 64);
            u16x8 hva = *(const u16x8*)&h1b[(size_t)sa * 256 + hl * 8];
            float wa = headL ? wa1 : wa0;
            sumw += wa;
#pragma unroll
            for (int c = 0; c < 8; ++c) acc[c] += wa * bf16_to_f(hva[c]);
        }
    }
#pragma unroll
    for (int c = 0; c < 8; ++c) acc[c] += __shfl_xor(acc[c], 32, 64);
    sumw += __shfl_xor(sumw, 32, 64);
    float inv = 1.0f / sumw;
    int ch = hl * 8 + half * 4;
    float4 bv = *(const float4*)&b1[ch];
    float bb[4] = {bv.x, bv.y, bv.z, bv.w};
    unsigned short o[4];
#pragma unroll
    for (int c = 0; c < 4; ++c) {
        float v = acc[half * 4 + c] * inv + bb[c];
        v = v > 0.f ? v : expm1f(v);
        o[c] = bf16_rne(v);
    }
    *(u16x4*)&helu_b[(size_t)wid * 256 + ch] = *(u16x4*)o;
}

// ---------------- GEMM2: bf16-A x split-bf16-B MFMA, alpha2 fused ----------
__global__ __launch_bounds__(256) void k_gemm2(const unsigned short* __restrict__ hb,
                                               const unsigned short* __restrict__ Whi,
                                               const unsigned short* __restrict__ Wlo,
                                               const float* __restrict__ a2s,
                                               const float* __restrict__ a2d,
                                               unsigned short* __restrict__ h2b,
                                               float* __restrict__ as_,
                                               float* __restrict__ ad_, int M) {
    __shared__ unsigned short sA[128 * G1S];
    __shared__ unsigned short sBh[64 * G1S], sBl[64 * G1S];
    int t = threadIdx.x;
    int lane = t & 63, wave = t >> 6;
    int q = lane >> 4, m = lane & 15;
    int row0 = blockIdx.x * 128;
    int rbase = wave * 32;
    f32x4 acc[2][4];
#pragma unroll
    for (int i = 0; i < 2; ++i)
#pragma unroll
        for (int j = 0; j < 4; ++j) acc[i][j] = (f32x4){0.f, 0.f, 0.f, 0.f};

    for (int kc = 0; kc < 256; kc += 32) {
#pragma unroll
        for (int i = 0; i < 2; ++i) {
            int slot = t + i * 256;
            int r = slot >> 2, kg = slot & 3;
            int row = row0 + r;
            u16x8 v = {0, 0, 0, 0, 0, 0, 0, 0};
            if (row < M) v = *(const u16x8*)&hb[(size_t)row * 256 + kc + kg * 8];
            *(u16x8*)&sA[r * G1S + kg * 8] = v;
        }
        {
            int n = t >> 2, kg = t & 3;
            *(u16x8*)&sBh[n * G1S + kg * 8] =
                *(const u16x8*)&Whi[(size_t)n * 256 + kc + kg * 8];
            *(u16x8*)&sBl[n * G1S + kg * 8] =
                *(const u16x8*)&Wlo[(size_t)n * 256 + kc + kg * 8];
        }
        __syncthreads();
        bf16x8 a[2], bh[4], bl[4];
#pragma unroll
        for (int i = 0; i < 2; ++i)
            a[i] = *(bf16x8*)&sA[(rbase + i * 16 + m) * G1S + q * 8];
#pragma unroll
        for (int j = 0; j < 4; ++j) {
            bh[j] = *(bf16x8*)&sBh[(j * 16 + m) * G1S + q * 8];
            bl[j] = *(bf16x8*)&sBl[(j * 16 + m) * G1S + q * 8];
        }
#pragma unroll
        for (int i = 0; i < 2; ++i)
#pragma unroll
            for (int j = 0; j < 4; ++j) {
                acc[i][j] = __builtin_amdgcn_mfma_f32_16x16x32_bf16(a[i], bl[j], acc[i][j], 0, 0, 0);
                acc[i][j] = __builtin_amdgcn_mfma_f32_16x16x32_bf16(a[i], bh[j], acc[i][j], 0, 0, 0);
            }
        __syncthreads();
    }
    float sv[4], dv[4];
#pragma unroll
    for (int j = 0; j < 4; ++j) {
        sv[j] = a2s[j * 16 + m];
        dv[j] = a2d[j * 16 + m];
    }
#pragma unroll
    for (int i = 0; i < 2; ++i) {
#pragma unroll
        for (int r = 0; r < 4; ++r) {
            int row = row0 + rbase + i * 16 + q * 4 + r;
            float ps = acc[i][0][r] * sv[0] + acc[i][1][r] * sv[1]
                     + acc[i][2][r] * sv[2] + acc[i][3][r] * sv[3];
            float pd = acc[i][0][r] * dv[0] + acc[i][1][r] * dv[1]
                     + acc[i][2][r] * dv[2] + acc[i][3][r] * dv[3];
#pragma unroll
            for (int mask = 1; mask < 16; mask <<= 1) {
                ps += __shfl_xor(ps, mask, 64);
                pd += __shfl_xor(pd, mask, 64);
            }
            if (row < M) {
#pragma unroll
                for (int j = 0; j < 4; ++j)
                    h2b[(size_t)row * 64 + j * 16 + m] = bf16_rne(acc[i][j][r]);
                if (m == 0) { as_[row] = ps; ad_[row] = pd; }
            }
        }
    }
}

// ------- layer-2 aggregate: inline w, quarter-wave/edge, 2-in-flight --------
__global__ __launch_bounds__(256) void k_agg2(const unsigned short* __restrict__ h2b,
                                              const float* __restrict__ as,
                                              const float* __restrict__ ad,
                                              const int* __restrict__ off,
                                              const int* __restrict__ srcl,
                                              const float* __restrict__ b2,
                                              float* __restrict__ out, int N) {
    int wid = (blockIdx.x * blockDim.x + threadIdx.x) >> 6;
    int lane = threadIdx.x & 63;
    if (wid >= N) return;
    int p0 = off[wid], p1 = off[wid + 1];
    float adw = ad[wid];
    int g = lane >> 4, gl = lane & 15;
    float acc[4];
#pragma unroll
    for (int c = 0; c < 4; ++c) acc[c] = 0.f;
    float sumw = 0.f;
    for (int base = p0; base < p1; base += 64) {
        int p = base + lane;
        int cnt = min(64, p1 - base);
        int s = 0; float w = 0.f;
        if (p < p1) {
            s = srcl[p];
            float l = as[s] + adw;
            l = l >= 0.f ? l : NSLOPE * l;
            w = __expf(l);
        }
        int quads = (cnt + 3) >> 2;
        int jj = 0;
        for (; jj + 2 <= quads; jj += 2) {
            int e0 = 4 * jj + g, e1 = e0 + 4;
            int sa = __shfl(s, e0, 64), sb = __shfl(s, e1, 64);
            float wa = __shfl(w, e0, 64), wb = __shfl(w, e1, 64);
            u16x4 hva = *(const u16x4*)&h2b[(size_t)sa * 64 + gl * 4];
            u16x4 hvb = *(const u16x4*)&h2b[(size_t)sb * 64 + gl * 4];
            sumw += wa + wb;
            acc[0] += wa * bf16_to_f(hva.x) + wb * bf16_to_f(hvb.x);
            acc[1] += wa * bf16_to_f(hva.y) + wb * bf16_to_f(hvb.y);
            acc[2] += wa * bf16_to_f(hva.z) + wb * bf16_to_f(hvb.z);
            acc[3] += wa * bf16_to_f(hva.w) + wb * bf16_to_f(hvb.w);
        }
        for (; jj < quads; ++jj) {
            int e0 = 4 * jj + g;
            int sa = __shfl(s, e0, 64);
            float wa = __shfl(w, e0, 64);
            u16x4 hva = *(const u16x4*)&h2b[(size_t)sa * 64 + gl * 4];
            sumw += wa;
            acc[0] += wa * bf16_to_f(hva.x);
            acc[1] += wa * bf16_to_f(hva.y);
            acc[2] += wa * bf16_to_f(hva.z);
            acc[3] += wa * bf16_to_f(hva.w);
        }
    }
#pragma unroll
    for (int c = 0; c < 4; ++c) {
        acc[c] += __shfl_xor(acc[c], 16, 64);
        acc[c] += __shfl_xor(acc[c], 32, 64);
    }
    sumw += __shfl_xor(sumw, 16, 64);
    sumw += __shfl_xor(sumw, 32, 64);
    if (g == 0) {
        float inv = 1.0f / sumw;
        float4 bv = *(const float4*)&b2[gl * 4];
        float4 o;
        o.x = acc[0] * inv + bv.x;
        o.y = acc[1] * inv + bv.y;
        o.z = acc[2] * inv + bv.z;
        o.w = acc[3] * inv + bv.w;
        *(float4*)&out[(size_t)wid * 64 + gl * 4] = o;
    }
}

// ---------------- launch ----------------
extern "C" void kernel_launch(void* const* d_in, const int* in_sizes, int n_in,
                              void* d_out, int out_size, void* d_ws, size_t ws_size,
                              hipStream_t stream) {
    if (n_in < 10) return;
    const float* x   = (const float*)d_in[0];
    const int*   ei  = (const int*)d_in[1];
    const float* W1  = (const float*)d_in[2];
    const float* a1s = (const float*)d_in[3];
    const float* a1d = (const float*)d_in[4];
    const float* b1  = (const float*)d_in[5];
    const float* W2  = (const float*)d_in[6];
    const float* a2s = (const float*)d_in[7];
    const float* a2d = (const float*)d_in[8];
    const float* b2  = (const float*)d_in[9];
    float* out = (float*)d_out;

    const int N = in_sizes[0] / 256;
    const int E = in_sizes[1] / 2;
    const int T = E + N;
    const int* esrc = ei;
    const int* edst = ei + E;

    char* ws = (char*)d_ws;
    size_t o = 0;
    auto alloc = [&](size_t bytes) -> void* {
        void* p = ws + o;
        o = (o + bytes + 255) & ~(size_t)255;
        return p;
    };
    unsigned short* h1b    = (unsigned short*)alloc((size_t)N * 256 * 2);
    unsigned short* helu_b = (unsigned short*)alloc((size_t)N * 256 * 2);
    unsigned short* W1hi   = (unsigned short*)alloc(256 * 256 * 2);
    unsigned short* W1lo   = (unsigned short*)alloc(256 * 256 * 2);
    unsigned short* W2hi   = (unsigned short*)alloc(64 * 256 * 2);
    unsigned short* W2lo   = (unsigned short*)alloc(64 * 256 * 2);
    unsigned short* h2b    = (unsigned short*)alloc((size_t)N * 64 * 2);
    float* al1s = (float*)alloc((size_t)N * 2 * 4);
    float* al1d = (float*)alloc((size_t)N * 2 * 4);
    float* al2s = (float*)alloc((size_t)N * 4);
    float* al2d = (float*)alloc((size_t)N * 4);
    int* deg  = (int*)alloc((size_t)(N + 64) * 4);  // deg[N] + ticket counter
    int* ticket = deg + N;
    int* off  = (int*)alloc((size_t)(N + 1) * 4);
    int* cur  = (int*)alloc((size_t)N * 4);
    int* part = (int*)alloc(256 * 4);
    int* srcl = (int*)alloc((size_t)T * 4);
    if (o > ws_size) return;

    const int CH = (N + 255) / 256;
    const int BH = (E + 255) / 256;

    hipMemsetAsync(deg, 0, (size_t)(N + 64) * 4, stream);
    k_prep_all<<<128 + BH, 256, 0, stream>>>(W1, W2, edst, W1hi, W1lo,
                                             W2hi, W2lo, deg, E);
    k_scan_ab<<<256, 256, 0, stream>>>(deg, part, ticket, &off[N], N, CH);
    k_scan_c<<<256, 256, 0, stream>>>(deg, part, off, cur, srcl, N, CH);
    k_fill<<<(E + 255) / 256, 256, 0, stream>>>(esrc, edst, cur, srcl, E);

    // layer 1
    k_gemm1<<<(N + 127) / 128, 256, 0, stream>>>(x, W1hi, W1lo, a1s, a1d,
                                                 h1b, al1s, al1d, N);
    k_agg1<<<(N + 3) / 4, 256, 0, stream>>>(h1b, al1s, al1d, off, srcl, b1, helu_b, N);

    // layer 2
    k_gemm2<<<(N + 127) / 128, 256, 0, stream>>>(helu_b, W2hi, W2lo, a2s, a2d,
                                                 h2b, al2s, al2d, N);
    k_agg2<<<(N + 3) / 4, 256, 0, stream>>>(h2b, al2s, al2d, off, srcl, b2, out, N);
}

// Round 8
// 309.822 us; speedup vs baseline: 1.0250x; 1.0250x over previous
//
#include <hip/hip_runtime.h>
#include <hip/hip_bf16.h>
#include <math.h>

// GAT encoder, round 8.  9 dispatches (round-6 structure):
//  memset | prep_all (split W1,W2 + dst hist) | scan_ab | scan_c | fill |
//  gemm1 (128x128 per-head tile, fp32-A in-register hi/lo split, alpha1 fused) |
//  agg1 | gemm2 | agg2.
// Round-7 lesson: 128x256 tile -> VGPR 192 + 61KB LDS -> 7% occupancy, 80 us.
// Keep 128x128 (3 blocks/CU) and do the fp32->hi/lo split in-kernel instead.

#define NSLOPE 0.2f

using bf16x8 = __attribute__((ext_vector_type(8))) short;
using f32x4  = __attribute__((ext_vector_type(4))) float;
using u16x8  = __attribute__((ext_vector_type(8))) unsigned short;
using u16x4  = __attribute__((ext_vector_type(4))) unsigned short;

__device__ __forceinline__ unsigned short bf16_rne(float f) {
    unsigned u = __float_as_uint(f);
    return (unsigned short)((u + 0x7FFFu + ((u >> 16) & 1u)) >> 16);
}
__device__ __forceinline__ float bf16_to_f(unsigned short h) {
    return __uint_as_float(((unsigned)h) << 16);
}

// ---------------- merged prep: prepW1 | prepW2 | hist ----------------
__global__ __launch_bounds__(256) void k_prep_all(const float* __restrict__ W1,
                                                  const float* __restrict__ W2,
                                                  const int* __restrict__ edst,
                                                  unsigned short* __restrict__ W1hi,
                                                  unsigned short* __restrict__ W1lo,
                                                  unsigned short* __restrict__ W2hi,
                                                  unsigned short* __restrict__ W2lo,
                                                  int* __restrict__ deg, int E) {
    int b = blockIdx.x, t = threadIdx.x;
    if (b < 64) {  // split+transpose W1 [256,256] -> [n][k]
        int id = b * 256 + t;
        int n = id >> 6, kg = id & 63;
        unsigned short hi[4], lo[4];
#pragma unroll
        for (int c = 0; c < 4; ++c) {
            float w = W1[(kg * 4 + c) * 256 + n];
            unsigned short h = bf16_rne(w);
            hi[c] = h;
            lo[c] = bf16_rne(w - bf16_to_f(h));
        }
        *(u16x4*)&W1hi[n * 256 + kg * 4] = *(u16x4*)hi;
        *(u16x4*)&W1lo[n * 256 + kg * 4] = *(u16x4*)lo;
    } else if (b < 128) {  // split+transpose W2 [256,64] -> [n][k]
        int id = (b - 64) * 256 + t;
        int n = id >> 8, k = id & 255;
        float w = W2[k * 64 + n];
        unsigned short h = bf16_rne(w);
        W2hi[n * 256 + k] = h;
        W2lo[n * 256 + k] = bf16_rne(w - bf16_to_f(h));
    } else {  // dst-degree histogram
        int i = (b - 128) * 256 + t;
        if (i < E) atomicAdd(&deg[edst[i]], 1);
    }
}

// -------- fused scan: per-block sums + last-block scans the 256 partials -----
__global__ __launch_bounds__(256) void k_scan_ab(const int* __restrict__ deg,
                                                 int* __restrict__ part,
                                                 int* __restrict__ ticket,
                                                 int* __restrict__ off_n,
                                                 int n, int CH) {
    __shared__ int sd[256];
    __shared__ int lastflag;
    int b = blockIdx.x, t = threadIdx.x;
    int s = b * CH, e = min(n, s + CH);
    int loc = 0;
    for (int i = s + t; i < e; i += 256) loc += deg[i] + 1;  // +1 self-loop
    sd[t] = loc;
    __syncthreads();
    for (int o = 128; o > 0; o >>= 1) {
        if (t < o) sd[t] += sd[t + o];
        __syncthreads();
    }
    if (t == 0) {
        part[b] = sd[0];
        __threadfence();
        int old = atomicAdd(ticket, 1);
        lastflag = (old == (int)gridDim.x - 1);
    }
    __syncthreads();
    if (lastflag) {
        __threadfence();
        int v = ((volatile int*)part)[t];
        sd[t] = v;
        __syncthreads();
        for (int o = 1; o < 256; o <<= 1) {
            int u = (t >= o) ? sd[t - o] : 0;
            __syncthreads();
            sd[t] += u;
            __syncthreads();
        }
        part[t] = sd[t] - v;  // exclusive base per block
        if (t == 255) *off_n = sd[255];
    }
}

__global__ __launch_bounds__(256) void k_scan_c(const int* __restrict__ deg,
                                                const int* __restrict__ part,
                                                int* __restrict__ off,
                                                int* __restrict__ cur,
                                                int* __restrict__ srcl, int n, int CH) {
    __shared__ int sd[256];
    int b = blockIdx.x, t = threadIdx.x;
    int s = b * CH, e = min(n, s + CH);
    int base = part[b];
    for (int c = s; c < e; c += 256) {
        int i = c + t;
        int v = (i < e) ? (deg[i] + 1) : 0;
        sd[t] = v;
        __syncthreads();
        for (int o = 1; o < 256; o <<= 1) {
            int u = (t >= o) ? sd[t - o] : 0;
            __syncthreads();
            sd[t] += u;
            __syncthreads();
        }
        if (i < e) {
            int ex = base + sd[t] - v;
            off[i] = ex;
            cur[i] = ex + 1;   // slot ex holds the self-loop
            srcl[ex] = i;
        }
        base += sd[255];
        __syncthreads();
    }
}

__global__ void k_fill(const int* __restrict__ src, const int* __restrict__ dst,
                       int* cur, int* __restrict__ srcl, int E) {
    int i = blockIdx.x * blockDim.x + threadIdx.x;
    if (i >= E) return;
    int s = src[i], d = dst[i];
    int p = atomicAdd(&cur[d], 1);
    srcl[p] = s;
}

// -- GEMM1: fp32-A in-register split, 128x128 tile (blockIdx.y=head), alpha1 fused
#define G1S 40  // LDS row stride in ushort (32 k + 8 pad)
__global__ __launch_bounds__(256) void k_gemm1(const float* __restrict__ x,
                                               const unsigned short* __restrict__ Whi,
                                               const unsigned short* __restrict__ Wlo,
                                               const float* __restrict__ a1s,
                                               const float* __restrict__ a1d,
                                               unsigned short* __restrict__ h1b,
                                               float* __restrict__ as_,
                                               float* __restrict__ ad_, int M) {
    __shared__ unsigned short sAh[128 * G1S], sAl[128 * G1S];
    __shared__ unsigned short sBh[128 * G1S], sBl[128 * G1S];
    __shared__ float salS[128][2], salD[128][2];
    int t = threadIdx.x;
    int lane = t & 63, wave = t >> 6;
    int q = lane >> 4, m = lane & 15;
    int row0 = blockIdx.x * 128;
    int head = blockIdx.y;
    int col0 = head * 128;
    int rbase = (wave & 1) * 64, cbase = (wave >> 1) * 64;
    f32x4 acc[4][4];
#pragma unroll
    for (int i = 0; i < 4; ++i)
#pragma unroll
        for (int j = 0; j < 4; ++j) acc[i][j] = (f32x4){0.f, 0.f, 0.f, 0.f};

    for (int kc = 0; kc < 256; kc += 32) {
        // stage A: 128 rows x 32 k from fp32 x, hi/lo split in registers
#pragma unroll
        for (int i2 = 0; i2 < 4; ++i2) {
            int slot = t + i2 * 256;           // 0..1023
            int r = slot >> 3, kg = slot & 7;  // r:0..127, kg: float4 chunk 0..7
            int row = row0 + r;
            float4 v = make_float4(0.f, 0.f, 0.f, 0.f);
            if (row < M) v = *(const float4*)&x[(size_t)row * 256 + kc + kg * 4];
            float vv[4] = {v.x, v.y, v.z, v.w};
            unsigned short hi[4], lo[4];
#pragma unroll
            for (int c = 0; c < 4; ++c) {
                unsigned short h = bf16_rne(vv[c]);
                hi[c] = h;
                lo[c] = bf16_rne(vv[c] - bf16_to_f(h));
            }
            *(u16x4*)&sAh[r * G1S + kg * 4] = *(u16x4*)hi;
            *(u16x4*)&sAl[r * G1S + kg * 4] = *(u16x4*)lo;
        }
        // stage B: 128 cols x 32 k (hi+lo), pre-transposed W [n][k]
#pragma unroll
        for (int i2 = 0; i2 < 2; ++i2) {
            int slot = t + i2 * 256;
            int n = slot >> 2, kg = slot & 3;
            *(u16x8*)&sBh[n * G1S + kg * 8] =
                *(const u16x8*)&Whi[(size_t)(col0 + n) * 256 + kc + kg * 8];
            *(u16x8*)&sBl[n * G1S + kg * 8] =
                *(const u16x8*)&Wlo[(size_t)(col0 + n) * 256 + kc + kg * 8];
        }
        __syncthreads();
        bf16x8 ah[4], al[4], bh[4], bl[4];
#pragma unroll
        for (int i = 0; i < 4; ++i) {
            int r = (rbase + i * 16 + m) * G1S + q * 8;
            ah[i] = *(bf16x8*)&sAh[r];
            al[i] = *(bf16x8*)&sAl[r];
        }
#pragma unroll
        for (int j = 0; j < 4; ++j) {
            int r = (cbase + j * 16 + m) * G1S + q * 8;
            bh[j] = *(bf16x8*)&sBh[r];
            bl[j] = *(bf16x8*)&sBl[r];
        }
#pragma unroll
        for (int i = 0; i < 4; ++i)
#pragma unroll
            for (int j = 0; j < 4; ++j) {
                acc[i][j] = __builtin_amdgcn_mfma_f32_16x16x32_bf16(ah[i], bl[j], acc[i][j], 0, 0, 0);
                acc[i][j] = __builtin_amdgcn_mfma_f32_16x16x32_bf16(al[i], bh[j], acc[i][j], 0, 0, 0);
                acc[i][j] = __builtin_amdgcn_mfma_f32_16x16x32_bf16(ah[i], bh[j], acc[i][j], 0, 0, 0);
            }
        __syncthreads();
    }
    float sv[4], dv[4];
#pragma unroll
    for (int j = 0; j < 4; ++j) {
        sv[j] = a1s[head * 128 + cbase + j * 16 + m];
        dv[j] = a1d[head * 128 + cbase + j * 16 + m];
    }
#pragma unroll
    for (int i = 0; i < 4; ++i) {
#pragma unroll
        for (int r = 0; r < 4; ++r) {
            int rl = rbase + i * 16 + q * 4 + r;
            int row = row0 + rl;
            float ps = acc[i][0][r] * sv[0] + acc[i][1][r] * sv[1]
                     + acc[i][2][r] * sv[2] + acc[i][3][r] * sv[3];
            float pd = acc[i][0][r] * dv[0] + acc[i][1][r] * dv[1]
                     + acc[i][2][r] * dv[2] + acc[i][3][r] * dv[3];
#pragma unroll
            for (int mask = 1; mask < 16; mask <<= 1) {
                ps += __shfl_xor(ps, mask, 64);
                pd += __shfl_xor(pd, mask, 64);
            }
            if (m == 0) {
                salS[rl][cbase >> 6] = ps;
                salD[rl][cbase >> 6] = pd;
            }
            if (row < M) {
#pragma unroll
                for (int j = 0; j < 4; ++j)
                    h1b[(size_t)row * 256 + col0 + cbase + j * 16 + m] = bf16_rne(acc[i][j][r]);
            }
        }
    }
    __syncthreads();
    if (t < 128) {
        int row = row0 + t;
        if (row < M) {
            as_[row * 2 + head] = salS[t][0] + salS[t][1];
            ad_[row * 2 + head] = salD[t][0] + salD[t][1];
        }
    }
}

// ------- layer-1 aggregate: inline softmax-w, half-wave/edge, 2-in-flight ----
__global__ __launch_bounds__(256) void k_agg1(const unsigned short* __restrict__ h1b,
                                              const float* __restrict__ as,
                                              const float* __restrict__ ad,
                                              const int* __restrict__ off,
                                              const int* __restrict__ srcl,
                                              const float* __restrict__ b1,
                                              unsigned short* __restrict__ helu_b, int N) {
    int wid = (blockIdx.x * blockDim.x + threadIdx.x) >> 6;
    int lane = threadIdx.x & 63;
    if (wid >= N) return;
    int p0 = off[wid], p1 = off[wid + 1];
    float ad0 = ad[wid * 2], ad1 = ad[wid * 2 + 1];
    int half = lane >> 5, hl = lane & 31;
    int headL = hl >> 4;
    float acc[8];
#pragma unroll
    for (int c = 0; c < 8; ++c) acc[c] = 0.f;
    float sumw = 0.f;
    for (int base = p0; base < p1; base += 64) {
        int p = base + lane;
        int cnt = min(64, p1 - base);
        int s = 0; float w0 = 0.f, w1 = 0.f;
        if (p < p1) {
            s = srcl[p];
            float2 av = *(const float2*)&as[s * 2];
            float l0 = av.x + ad0; l0 = l0 >= 0.f ? l0 : NSLOPE * l0;
            float l1 = av.y + ad1; l1 = l1 >= 0.f ? l1 : NSLOPE * l1;
            w0 = __expf(l0); w1 = __expf(l1);
        }
        int pairs = (cnt + 1) >> 1;
        int jj = 0;
        for (; jj + 2 <= pairs; jj += 2) {
            int e0 = 2 * jj + half, e1 = e0 + 2;
            int sa = __shfl(s, e0, 64), sb = __shfl(s, e1, 64);
            float wa0 = __shfl(w0, e0, 64), wa1 = __shfl(w1, e0, 64);
            float wb0 = __shfl(w0, e1, 64), wb1 = __shfl(w1, e1, 64);
            u16x8 hva = *(const u16x8*)&h1b[(size_t)sa * 256 + hl * 8];
            u16x8 hvb = *(const u16x8*)&h1b[(size_t)sb * 256 + hl * 8];
            float wa = headL ? wa1 : wa0;
            float wb = headL ? wb1 : wb0;
            sumw += wa + wb;
#pragma unroll
            for (int c = 0; c < 8; ++c)
                acc[c] += wa * bf16_to_f(hva[c]) + wb * bf16_to_f(hvb[c]);
        }
        for (; jj < pairs; ++jj) {
            int e0 = 2 * jj + half;
            int sa = __shfl(s, e0, 64);
            float wa0 = __shfl(w0, e0, 64), wa1 = __shfl(w1, e0, 64);
            u16x8 hva = *(const u16x8*)&h1b[(size_t)sa * 256 + hl * 8];
            float wa = headL ? wa1 : wa0;
            sumw += wa;
#pragma unroll
            for (int c = 0; c < 8; ++c) acc[c] += wa * bf16_to_f(hva[c]);
        }
    }
#pragma unroll
    for (int c = 0; c < 8; ++c) acc[c] += __shfl_xor(acc[c], 32, 64);
    sumw += __shfl_xor(sumw, 32, 64);
    float inv = 1.0f / sumw;
    int ch = hl * 8 + half * 4;
    float4 bv = *(const float4*)&b1[ch];
    float bb[4] = {bv.x, bv.y, bv.z, bv.w};
    unsigned short o[4];
#pragma unroll
    for (int c = 0; c < 4; ++c) {
        float v = acc[half * 4 + c] * inv + bb[c];
        v = v > 0.f ? v : expm1f(v);
        o[c] = bf16_rne(v);
    }
    *(u16x4*)&helu_b[(size_t)wid * 256 + ch] = *(u16x4*)o;
}

// ---------------- GEMM2: bf16-A x split-bf16-B MFMA, alpha2 fused ----------
__global__ __launch_bounds__(256) void k_gemm2(const unsigned short* __restrict__ hb,
                                               const unsigned short* __restrict__ Whi,
                                               const unsigned short* __restrict__ Wlo,
                                               const float* __restrict__ a2s,
                                               const float* __restrict__ a2d,
                                               unsigned short* __restrict__ h2b,
                                               float* __restrict__ as_,
                                               float* __restrict__ ad_, int M) {
    __shared__ unsigned short sA[128 * G1S];
    __shared__ unsigned short sBh[64 * G1S], sBl[64 * G1S];
    int t = threadIdx.x;
    int lane = t & 63, wave = t >> 6;
    int q = lane >> 4, m = lane & 15;
    int row0 = blockIdx.x * 128;
    int rbase = wave * 32;
    f32x4 acc[2][4];
#pragma unroll
    for (int i = 0; i < 2; ++i)
#pragma unroll
        for (int j = 0; j < 4; ++j) acc[i][j] = (f32x4){0.f, 0.f, 0.f, 0.f};

    for (int kc = 0; kc < 256; kc += 32) {
#pragma unroll
        for (int i = 0; i < 2; ++i) {
            int slot = t + i * 256;
            int r = slot >> 2, kg = slot & 3;
            int row = row0 + r;
            u16x8 v = {0, 0, 0, 0, 0, 0, 0, 0};
            if (row < M) v = *(const u16x8*)&hb[(size_t)row * 256 + kc + kg * 8];
            *(u16x8*)&sA[r * G1S + kg * 8] = v;
        }
        {
            int n = t >> 2, kg = t & 3;
            *(u16x8*)&sBh[n * G1S + kg * 8] =
                *(const u16x8*)&Whi[(size_t)n * 256 + kc + kg * 8];
            *(u16x8*)&sBl[n * G1S + kg * 8] =
                *(const u16x8*)&Wlo[(size_t)n * 256 + kc + kg * 8];
        }
        __syncthreads();
        bf16x8 a[2], bh[4], bl[4];
#pragma unroll
        for (int i = 0; i < 2; ++i)
            a[i] = *(bf16x8*)&sA[(rbase + i * 16 + m) * G1S + q * 8];
#pragma unroll
        for (int j = 0; j < 4; ++j) {
            bh[j] = *(bf16x8*)&sBh[(j * 16 + m) * G1S + q * 8];
            bl[j] = *(bf16x8*)&sBl[(j * 16 + m) * G1S + q * 8];
        }
#pragma unroll
        for (int i = 0; i < 2; ++i)
#pragma unroll
            for (int j = 0; j < 4; ++j) {
                acc[i][j] = __builtin_amdgcn_mfma_f32_16x16x32_bf16(a[i], bl[j], acc[i][j], 0, 0, 0);
                acc[i][j] = __builtin_amdgcn_mfma_f32_16x16x32_bf16(a[i], bh[j], acc[i][j], 0, 0, 0);
            }
        __syncthreads();
    }
    float sv[4], dv[4];
#pragma unroll
    for (int j = 0; j < 4; ++j) {
        sv[j] = a2s[j * 16 + m];
        dv[j] = a2d[j * 16 + m];
    }
#pragma unroll
    for (int i = 0; i < 2; ++i) {
#pragma unroll
        for (int r = 0; r < 4; ++r) {
            int row = row0 + rbase + i * 16 + q * 4 + r;
            float ps = acc[i][0][r] * sv[0] + acc[i][1][r] * sv[1]
                     + acc[i][2][r] * sv[2] + acc[i][3][r] * sv[3];
            float pd = acc[i][0][r] * dv[0] + acc[i][1][r] * dv[1]
                     + acc[i][2][r] * dv[2] + acc[i][3][r] * dv[3];
#pragma unroll
            for (int mask = 1; mask < 16; mask <<= 1) {
                ps += __shfl_xor(ps, mask, 64);
                pd += __shfl_xor(pd, mask, 64);
            }
            if (row < M) {
#pragma unroll
                for (int j = 0; j < 4; ++j)
                    h2b[(size_t)row * 64 + j * 16 + m] = bf16_rne(acc[i][j][r]);
                if (m == 0) { as_[row] = ps; ad_[row] = pd; }
            }
        }
    }
}

// ------- layer-2 aggregate: inline w, quarter-wave/edge, 2-in-flight --------
__global__ __launch_bounds__(256) void k_agg2(const unsigned short* __restrict__ h2b,
                                              const float* __restrict__ as,
                                              const float* __restrict__ ad,
                                              const int* __restrict__ off,
                                              const int* __restrict__ srcl,
                                              const float* __restrict__ b2,
                                              float* __restrict__ out, int N) {
    int wid = (blockIdx.x * blockDim.x + threadIdx.x) >> 6;
    int lane = threadIdx.x & 63;
    if (wid >= N) return;
    int p0 = off[wid], p1 = off[wid + 1];
    float adw = ad[wid];
    int g = lane >> 4, gl = lane & 15;
    float acc[4];
#pragma unroll
    for (int c = 0; c < 4; ++c) acc[c] = 0.f;
    float sumw = 0.f;
    for (int base = p0; base < p1; base += 64) {
        int p = base + lane;
        int cnt = min(64, p1 - base);
        int s = 0; float w = 0.f;
        if (p < p1) {
            s = srcl[p];
            float l = as[s] + adw;
            l = l >= 0.f ? l : NSLOPE * l;
            w = __expf(l);
        }
        int quads = (cnt + 3) >> 2;
        int jj = 0;
        for (; jj + 2 <= quads; jj += 2) {
            int e0 = 4 * jj + g, e1 = e0 + 4;
            int sa = __shfl(s, e0, 64), sb = __shfl(s, e1, 64);
            float wa = __shfl(w, e0, 64), wb = __shfl(w, e1, 64);
            u16x4 hva = *(const u16x4*)&h2b[(size_t)sa * 64 + gl * 4];
            u16x4 hvb = *(const u16x4*)&h2b[(size_t)sb * 64 + gl * 4];
            sumw += wa + wb;
            acc[0] += wa * bf16_to_f(hva.x) + wb * bf16_to_f(hvb.x);
            acc[1] += wa * bf16_to_f(hva.y) + wb * bf16_to_f(hvb.y);
            acc[2] += wa * bf16_to_f(hva.z) + wb * bf16_to_f(hvb.z);
            acc[3] += wa * bf16_to_f(hva.w) + wb * bf16_to_f(hvb.w);
        }
        for (; jj < quads; ++jj) {
            int e0 = 4 * jj + g;
            int sa = __shfl(s, e0, 64);
            float wa = __shfl(w, e0, 64);
            u16x4 hva = *(const u16x4*)&h2b[(size_t)sa * 64 + gl * 4];
            sumw += wa;
            acc[0] += wa * bf16_to_f(hva.x);
            acc[1] += wa * bf16_to_f(hva.y);
            acc[2] += wa * bf16_to_f(hva.z);
            acc[3] += wa * bf16_to_f(hva.w);
        }
    }
#pragma unroll
    for (int c = 0; c < 4; ++c) {
        acc[c] += __shfl_xor(acc[c], 16, 64);
        acc[c] += __shfl_xor(acc[c], 32, 64);
    }
    sumw += __shfl_xor(sumw, 16, 64);
    sumw += __shfl_xor(sumw, 32, 64);
    if (g == 0) {
        float inv = 1.0f / sumw;
        float4 bv = *(const float4*)&b2[gl * 4];
        float4 o;
        o.x = acc[0] * inv + bv.x;
        o.y = acc[1] * inv + bv.y;
        o.z = acc[2] * inv + bv.z;
        o.w = acc[3] * inv + bv.w;
        *(float4*)&out[(size_t)wid * 64 + gl * 4] = o;
    }
}

// ---------------- launch ----------------
extern "C" void kernel_launch(void* const* d_in, const int* in_sizes, int n_in,
                              void* d_out, int out_size, void* d_ws, size_t ws_size,
                              hipStream_t stream) {
    if (n_in < 10) return;
    const float* x   = (const float*)d_in[0];
    const int*   ei  = (const int*)d_in[1];
    const float* W1  = (const float*)d_in[2];
    const float* a1s = (const float*)d_in[3];
    const float* a1d = (const float*)d_in[4];
    const float* b1  = (const float*)d_in[5];
    const float* W2  = (const float*)d_in[6];
    const float* a2s = (const float*)d_in[7];
    const float* a2d = (const float*)d_in[8];
    const float* b2  = (const float*)d_in[9];
    float* out = (float*)d_out;

    const int N = in_sizes[0] / 256;
    const int E = in_sizes[1] / 2;
    const int T = E + N;
    const int* esrc = ei;
    const int* edst = ei + E;

    char* ws = (char*)d_ws;
    size_t o = 0;
    auto alloc = [&](size_t bytes) -> void* {
        void* p = ws + o;
        o = (o + bytes + 255) & ~(size_t)255;
        return p;
    };
    unsigned short* h1b    = (unsigned short*)alloc((size_t)N * 256 * 2);
    unsigned short* helu_b = (unsigned short*)alloc((size_t)N * 256 * 2);
    unsigned short* W1hi   = (unsigned short*)alloc(256 * 256 * 2);
    unsigned short* W1lo   = (unsigned short*)alloc(256 * 256 * 2);
    unsigned short* W2hi   = (unsigned short*)alloc(64 * 256 * 2);
    unsigned short* W2lo   = (unsigned short*)alloc(64 * 256 * 2);
    unsigned short* h2b    = (unsigned short*)alloc((size_t)N * 64 * 2);
    float* al1s = (float*)alloc((size_t)N * 2 * 4);
    float* al1d = (float*)alloc((size_t)N * 2 * 4);
    float* al2s = (float*)alloc((size_t)N * 4);
    float* al2d = (float*)alloc((size_t)N * 4);
    int* deg  = (int*)alloc((size_t)(N + 64) * 4);  // deg[N] + ticket counter
    int* ticket = deg + N;
    int* off  = (int*)alloc((size_t)(N + 1) * 4);
    int* cur  = (int*)alloc((size_t)N * 4);
    int* part = (int*)alloc(256 * 4);
    int* srcl = (int*)alloc((size_t)T * 4);
    if (o > ws_size) return;

    const int CH = (N + 255) / 256;
    const int BH = (E + 255) / 256;

    hipMemsetAsync(deg, 0, (size_t)(N + 64) * 4, stream);
    k_prep_all<<<128 + BH, 256, 0, stream>>>(W1, W2, edst, W1hi, W1lo,
                                             W2hi, W2lo, deg, E);
    k_scan_ab<<<256, 256, 0, stream>>>(deg, part, ticket, &off[N], N, CH);
    k_scan_c<<<256, 256, 0, stream>>>(deg, part, off, cur, srcl, N, CH);
    k_fill<<<(E + 255) / 256, 256, 0, stream>>>(esrc, edst, cur, srcl, E);

    // layer 1
    dim3 g1((N + 127) / 128, 2);
    k_gemm1<<<g1, 256, 0, stream>>>(x, W1hi, W1lo, a1s, a1d, h1b, al1s, al1d, N);
    k_agg1<<<(N + 3) / 4, 256, 0, stream>>>(h1b, al1s, al1d, off, srcl, b1, helu_b, N);

    // layer 2
    k_gemm2<<<(N + 127) / 128, 256, 0, stream>>>(helu_b, W2hi, W2lo, a2s, a2d,
                                                 h2b, al2s, al2d, N);
    k_agg2<<<(N + 3) / 4, 256, 0, stream>>>(h2b, al2s, al2d, off, srcl, b2, out, N);
}

// Round 9
// 292.729 us; speedup vs baseline: 1.0848x; 1.0584x over previous
//
#include <hip/hip_runtime.h>
#include <hip/hip_bf16.h>
#include <math.h>

// GAT encoder, round 9.  9 dispatches (round-6 structure):
//  memset | prep_all (x->Xhi, split W1 hi/lo, W2->W2hi, dst hist) | scan_ab |
//  scan_c | fill | gemm1 (2-term: xhi x (W1hi+W1lo), 128x128/head, alpha1 fused) |
//  agg1 | gemm2 (1-term: helu_b x W2hi, alpha2 fused) | agg2.
// Precision budget: absmax was 0.0039 @ threshold 0.01625; x-bf16 and W2-bf16
// rounding each add ~2e-3-class error -> expected ~0.006-0.009.
// Round-7 lesson: keep 128x128 tiles (occupancy); round-8 lesson: pre-split A.

#define NSLOPE 0.2f

using bf16x8 = __attribute__((ext_vector_type(8))) short;
using f32x4  = __attribute__((ext_vector_type(4))) float;
using u16x8  = __attribute__((ext_vector_type(8))) unsigned short;
using u16x4  = __attribute__((ext_vector_type(4))) unsigned short;

__device__ __forceinline__ unsigned short bf16_rne(float f) {
    unsigned u = __float_as_uint(f);
    return (unsigned short)((u + 0x7FFFu + ((u >> 16) & 1u)) >> 16);
}
__device__ __forceinline__ float bf16_to_f(unsigned short h) {
    return __uint_as_float(((unsigned)h) << 16);
}

// -------- merged prep: x->Xhi | split W1 | W2->W2hi | hist --------
__global__ __launch_bounds__(256) void k_prep_all(const float* __restrict__ x,
                                                  const float* __restrict__ W1,
                                                  const float* __restrict__ W2,
                                                  const int* __restrict__ edst,
                                                  unsigned short* __restrict__ Xhi,
                                                  unsigned short* __restrict__ W1hi,
                                                  unsigned short* __restrict__ W1lo,
                                                  unsigned short* __restrict__ W2hi,
                                                  int* __restrict__ deg,
                                                  int BX, int total4, int E) {
    int b = blockIdx.x, t = threadIdx.x;
    if (b < BX) {  // x -> bf16 (hi only): 4 floats / thread
        int id = b * 256 + t;
        if (id >= total4) return;
        float4 v = *(const float4*)&x[(size_t)id * 4];
        unsigned short hi[4];
        hi[0] = bf16_rne(v.x); hi[1] = bf16_rne(v.y);
        hi[2] = bf16_rne(v.z); hi[3] = bf16_rne(v.w);
        *(u16x4*)&Xhi[(size_t)id * 4] = *(u16x4*)hi;
    } else if (b < BX + 64) {  // split+transpose W1 [256,256] -> [n][k]
        int id = (b - BX) * 256 + t;
        int n = id >> 6, kg = id & 63;
        unsigned short hi[4], lo[4];
#pragma unroll
        for (int c = 0; c < 4; ++c) {
            float w = W1[(kg * 4 + c) * 256 + n];
            unsigned short h = bf16_rne(w);
            hi[c] = h;
            lo[c] = bf16_rne(w - bf16_to_f(h));
        }
        *(u16x4*)&W1hi[n * 256 + kg * 4] = *(u16x4*)hi;
        *(u16x4*)&W1lo[n * 256 + kg * 4] = *(u16x4*)lo;
    } else if (b < BX + 128) {  // transpose W2 [256,64] -> [n][k], bf16
        int id = (b - BX - 64) * 256 + t;
        int n = id >> 8, k = id & 255;
        W2hi[n * 256 + k] = bf16_rne(W2[k * 64 + n]);
    } else {  // dst-degree histogram
        int i = (b - BX - 128) * 256 + t;
        if (i < E) atomicAdd(&deg[edst[i]], 1);
    }
}

// -------- fused scan: per-block sums + last-block scans the 256 partials -----
__global__ __launch_bounds__(256) void k_scan_ab(const int* __restrict__ deg,
                                                 int* __restrict__ part,
                                                 int* __restrict__ ticket,
                                                 int* __restrict__ off_n,
                                                 int n, int CH) {
    __shared__ int sd[256];
    __shared__ int lastflag;
    int b = blockIdx.x, t = threadIdx.x;
    int s = b * CH, e = min(n, s + CH);
    int loc = 0;
    for (int i = s + t; i < e; i += 256) loc += deg[i] + 1;  // +1 self-loop
    sd[t] = loc;
    __syncthreads();
    for (int o = 128; o > 0; o >>= 1) {
        if (t < o) sd[t] += sd[t + o];
        __syncthreads();
    }
    if (t == 0) {
        part[b] = sd[0];
        __threadfence();
        int old = atomicAdd(ticket, 1);
        lastflag = (old == (int)gridDim.x - 1);
    }
    __syncthreads();
    if (lastflag) {
        __threadfence();
        int v = ((volatile int*)part)[t];
        sd[t] = v;
        __syncthreads();
        for (int o = 1; o < 256; o <<= 1) {
            int u = (t >= o) ? sd[t - o] : 0;
            __syncthreads();
            sd[t] += u;
            __syncthreads();
        }
        part[t] = sd[t] - v;  // exclusive base per block
        if (t == 255) *off_n = sd[255];
    }
}

__global__ __launch_bounds__(256) void k_scan_c(const int* __restrict__ deg,
                                                const int* __restrict__ part,
                                                int* __restrict__ off,
                                                int* __restrict__ cur,
                                                int* __restrict__ srcl, int n, int CH) {
    __shared__ int sd[256];
    int b = blockIdx.x, t = threadIdx.x;
    int s = b * CH, e = min(n, s + CH);
    int base = part[b];
    for (int c = s; c < e; c += 256) {
        int i = c + t;
        int v = (i < e) ? (deg[i] + 1) : 0;
        sd[t] = v;
        __syncthreads();
        for (int o = 1; o < 256; o <<= 1) {
            int u = (t >= o) ? sd[t - o] : 0;
            __syncthreads();
            sd[t] += u;
            __syncthreads();
        }
        if (i < e) {
            int ex = base + sd[t] - v;
            off[i] = ex;
            cur[i] = ex + 1;   // slot ex holds the self-loop
            srcl[ex] = i;
        }
        base += sd[255];
        __syncthreads();
    }
}

__global__ void k_fill(const int* __restrict__ src, const int* __restrict__ dst,
                       int* cur, int* __restrict__ srcl, int E) {
    int i = blockIdx.x * blockDim.x + threadIdx.x;
    if (i >= E) return;
    int s = src[i], d = dst[i];
    int p = atomicAdd(&cur[d], 1);
    srcl[p] = s;
}

// -- GEMM1: 2-term xhi x (W1hi+W1lo), 128x128 tile (blockIdx.y=head), alpha1 fused
#define G1S 40  // LDS row stride in ushort (32 k + 8 pad)
__global__ __launch_bounds__(256) void k_gemm1(const unsigned short* __restrict__ Xhi,
                                               const unsigned short* __restrict__ Whi,
                                               const unsigned short* __restrict__ Wlo,
                                               const float* __restrict__ a1s,
                                               const float* __restrict__ a1d,
                                               unsigned short* __restrict__ h1b,
                                               float* __restrict__ as_,
                                               float* __restrict__ ad_, int M) {
    __shared__ unsigned short sAh[128 * G1S];
    __shared__ unsigned short sBh[128 * G1S], sBl[128 * G1S];
    __shared__ float salS[128][2], salD[128][2];
    int t = threadIdx.x;
    int lane = t & 63, wave = t >> 6;
    int q = lane >> 4, m = lane & 15;
    int row0 = blockIdx.x * 128;
    int head = blockIdx.y;
    int col0 = head * 128;
    int rbase = (wave & 1) * 64, cbase = (wave >> 1) * 64;
    f32x4 acc[4][4];
#pragma unroll
    for (int i = 0; i < 4; ++i)
#pragma unroll
        for (int j = 0; j < 4; ++j) acc[i][j] = (f32x4){0.f, 0.f, 0.f, 0.f};

    for (int kc = 0; kc < 256; kc += 32) {
        // stage A: 128 rows x 32 k (hi only), 512 u16x8 slots
#pragma unroll
        for (int i2 = 0; i2 < 2; ++i2) {
            int slot = t + i2 * 256;
            int r = slot >> 2, kg = slot & 3;
            int row = row0 + r;
            u16x8 vh = {0, 0, 0, 0, 0, 0, 0, 0};
            if (row < M) vh = *(const u16x8*)&Xhi[(size_t)row * 256 + kc + kg * 8];
            *(u16x8*)&sAh[r * G1S + kg * 8] = vh;
        }
        // stage B: 128 cols x 32 k (hi+lo), pre-transposed W [n][k]
#pragma unroll
        for (int i2 = 0; i2 < 2; ++i2) {
            int slot = t + i2 * 256;
            int n = slot >> 2, kg = slot & 3;
            *(u16x8*)&sBh[n * G1S + kg * 8] =
                *(const u16x8*)&Whi[(size_t)(col0 + n) * 256 + kc + kg * 8];
            *(u16x8*)&sBl[n * G1S + kg * 8] =
                *(const u16x8*)&Wlo[(size_t)(col0 + n) * 256 + kc + kg * 8];
        }
        __syncthreads();
        bf16x8 ah[4], bh[4], bl[4];
#pragma unroll
        for (int i = 0; i < 4; ++i)
            ah[i] = *(bf16x8*)&sAh[(rbase + i * 16 + m) * G1S + q * 8];
#pragma unroll
        for (int j = 0; j < 4; ++j) {
            int r = (cbase + j * 16 + m) * G1S + q * 8;
            bh[j] = *(bf16x8*)&sBh[r];
            bl[j] = *(bf16x8*)&sBl[r];
        }
#pragma unroll
        for (int i = 0; i < 4; ++i)
#pragma unroll
            for (int j = 0; j < 4; ++j) {
                acc[i][j] = __builtin_amdgcn_mfma_f32_16x16x32_bf16(ah[i], bl[j], acc[i][j], 0, 0, 0);
                acc[i][j] = __builtin_amdgcn_mfma_f32_16x16x32_bf16(ah[i], bh[j], acc[i][j], 0, 0, 0);
            }
        __syncthreads();
    }
    float sv[4], dv[4];
#pragma unroll
    for (int j = 0; j < 4; ++j) {
        sv[j] = a1s[head * 128 + cbase + j * 16 + m];
        dv[j] = a1d[head * 128 + cbase + j * 16 + m];
    }
#pragma unroll
    for (int i = 0; i < 4; ++i) {
#pragma unroll
        for (int r = 0; r < 4; ++r) {
            int rl = rbase + i * 16 + q * 4 + r;
            int row = row0 + rl;
            float ps = acc[i][0][r] * sv[0] + acc[i][1][r] * sv[1]
                     + acc[i][2][r] * sv[2] + acc[i][3][r] * sv[3];
            float pd = acc[i][0][r] * dv[0] + acc[i][1][r] * dv[1]
                     + acc[i][2][r] * dv[2] + acc[i][3][r] * dv[3];
#pragma unroll
            for (int mask = 1; mask < 16; mask <<= 1) {
                ps += __shfl_xor(ps, mask, 64);
                pd += __shfl_xor(pd, mask, 64);
            }
            if (m == 0) {
                salS[rl][cbase >> 6] = ps;
                salD[rl][cbase >> 6] = pd;
            }
            if (row < M) {
#pragma unroll
                for (int j = 0; j < 4; ++j)
                    h1b[(size_t)row * 256 + col0 + cbase + j * 16 + m] = bf16_rne(acc[i][j][r]);
            }
        }
    }
    __syncthreads();
    if (t < 128) {
        int row = row0 + t;
        if (row < M) {
            as_[row * 2 + head] = salS[t][0] + salS[t][1];
            ad_[row * 2 + head] = salD[t][0] + salD[t][1];
        }
    }
}

// ------- layer-1 aggregate: inline softmax-w, half-wave/edge, 2-in-flight ----
__global__ __launch_bounds__(256) void k_agg1(const unsigned short* __restrict__ h1b,
                                              const float* __restrict__ as,
                                              const float* __restrict__ ad,
                                              const int* __restrict__ off,
                                              const int* __restrict__ srcl,
                                              const float* __restrict__ b1,
                                              unsigned short* __restrict__ helu_b, int N) {
    int wid = (blockIdx.x * blockDim.x + threadIdx.x) >> 6;
    int lane = threadIdx.x & 63;
    if (wid >= N) return;
    int p0 = off[wid], p1 = off[wid + 1];
    float ad0 = ad[wid * 2], ad1 = ad[wid * 2 + 1];
    int half = lane >> 5, hl = lane & 31;
    int headL = hl >> 4;
    float acc[8];
#pragma unroll
    for (int c = 0; c < 8; ++c) acc[c] = 0.f;
    float sumw = 0.f;
    for (int base = p0; base < p1; base += 64) {
        int p = base + lane;
        int cnt = min(64, p1 - base);
        int s = 0; float w0 = 0.f, w1 = 0.f;
        if (p < p1) {
            s = srcl[p];
            float2 av = *(const float2*)&as[s * 2];
            float l0 = av.x + ad0; l0 = l0 >= 0.f ? l0 : NSLOPE * l0;
            float l1 = av.y + ad1; l1 = l1 >= 0.f ? l1 : NSLOPE * l1;
            w0 = __expf(l0); w1 = __expf(l1);
        }
        int pairs = (cnt + 1) >> 1;
        int jj = 0;
        for (; jj + 2 <= pairs; jj += 2) {
            int e0 = 2 * jj + half, e1 = e0 + 2;
            int sa = __shfl(s, e0, 64), sb = __shfl(s, e1, 64);
            float wa0 = __shfl(w0, e0, 64), wa1 = __shfl(w1, e0, 64);
            float wb0 = __shfl(w0, e1, 64), wb1 = __shfl(w1, e1, 64);
            u16x8 hva = *(const u16x8*)&h1b[(size_t)sa * 256 + hl * 8];
            u16x8 hvb = *(const u16x8*)&h1b[(size_t)sb * 256 + hl * 8];
            float wa = headL ? wa1 : wa0;
            float wb = headL ? wb1 : wb0;
            sumw += wa + wb;
#pragma unroll
            for (int c = 0; c < 8; ++c)
                acc[c] += wa * bf16_to_f(hva[c]) + wb * bf16_to_f(hvb[c]);
        }
        for (; jj < pairs; ++jj) {
            int e0 = 2 * jj + half;
            int sa = __shfl(s, e0, 64);
            float wa0 = __shfl(w0, e0, 64), wa1 = __shfl(w1, e0, 64);
            u16x8 hva = *(const u16x8*)&h1b[(size_t)sa * 256 + hl * 8];
            float wa = headL ? wa1 : wa0;
            sumw += wa;
#pragma unroll
            for (int c = 0; c < 8; ++c) acc[c] += wa * bf16_to_f(hva[c]);
        }
    }
#pragma unroll
    for (int c = 0; c < 8; ++c) acc[c] += __shfl_xor(acc[c], 32, 64);
    sumw += __shfl_xor(sumw, 32, 64);
    float inv = 1.0f / sumw;
    int ch = hl * 8 + half * 4;
    float4 bv = *(const float4*)&b1[ch];
    float bb[4] = {bv.x, bv.y, bv.z, bv.w};
    unsigned short o[4];
#pragma unroll
    for (int c = 0; c < 4; ++c) {
        float v = acc[half * 4 + c] * inv + bb[c];
        v = v > 0.f ? v : expm1f(v);
        o[c] = bf16_rne(v);
    }
    *(u16x4*)&helu_b[(size_t)wid * 256 + ch] = *(u16x4*)o;
}

// ---------------- GEMM2: 1-term bf16-A x bf16-B MFMA, alpha2 fused ----------
__global__ __launch_bounds__(256) void k_gemm2(const unsigned short* __restrict__ hb,
                                               const unsigned short* __restrict__ Whi,
                                               const float* __restrict__ a2s,
                                               const float* __restrict__ a2d,
                                               unsigned short* __restrict__ h2b,
                                               float* __restrict__ as_,
                                               float* __restrict__ ad_, int M) {
    __shared__ unsigned short sA[128 * G1S];
    __shared__ unsigned short sBh[64 * G1S];
    int t = threadIdx.x;
    int lane = t & 63, wave = t >> 6;
    int q = lane >> 4, m = lane & 15;
    int row0 = blockIdx.x * 128;
    int rbase = wave * 32;
    f32x4 acc[2][4];
#pragma unroll
    for (int i = 0; i < 2; ++i)
#pragma unroll
        for (int j = 0; j < 4; ++j) acc[i][j] = (f32x4){0.f, 0.f, 0.f, 0.f};

    for (int kc = 0; kc < 256; kc += 32) {
#pragma unroll
        for (int i = 0; i < 2; ++i) {
            int slot = t + i * 256;
            int r = slot >> 2, kg = slot & 3;
            int row = row0 + r;
            u16x8 v = {0, 0, 0, 0, 0, 0, 0, 0};
            if (row < M) v = *(const u16x8*)&hb[(size_t)row * 256 + kc + kg * 8];
            *(u16x8*)&sA[r * G1S + kg * 8] = v;
        }
        {
            int n = t >> 2, kg = t & 3;
            *(u16x8*)&sBh[n * G1S + kg * 8] =
                *(const u16x8*)&Whi[(size_t)n * 256 + kc + kg * 8];
        }
        __syncthreads();
        bf16x8 a[2], bh[4];
#pragma unroll
        for (int i = 0; i < 2; ++i)
            a[i] = *(bf16x8*)&sA[(rbase + i * 16 + m) * G1S + q * 8];
#pragma unroll
        for (int j = 0; j < 4; ++j)
            bh[j] = *(bf16x8*)&sBh[(j * 16 + m) * G1S + q * 8];
#pragma unroll
        for (int i = 0; i < 2; ++i)
#pragma unroll
            for (int j = 0; j < 4; ++j)
                acc[i][j] = __builtin_amdgcn_mfma_f32_16x16x32_bf16(a[i], bh[j], acc[i][j], 0, 0, 0);
        __syncthreads();
    }
    float sv[4], dv[4];
#pragma unroll
    for (int j = 0; j < 4; ++j) {
        sv[j] = a2s[j * 16 + m];
        dv[j] = a2d[j * 16 + m];
    }
#pragma unroll
    for (int i = 0; i < 2; ++i) {
#pragma unroll
        for (int r = 0; r < 4; ++r) {
            int row = row0 + rbase + i * 16 + q * 4 + r;
            float ps = acc[i][0][r] * sv[0] + acc[i][1][r] * sv[1]
                     + acc[i][2][r] * sv[2] + acc[i][3][r] * sv[3];
            float pd = acc[i][0][r] * dv[0] + acc[i][1][r] * dv[1]
                     + acc[i][2][r] * dv[2] + acc[i][3][r] * dv[3];
#pragma unroll
            for (int mask = 1; mask < 16; mask <<= 1) {
                ps += __shfl_xor(ps, mask, 64);
                pd += __shfl_xor(pd, mask, 64);
            }
            if (row < M) {
#pragma unroll
                for (int j = 0; j < 4; ++j)
                    h2b[(size_t)row * 64 + j * 16 + m] = bf16_rne(acc[i][j][r]);
                if (m == 0) { as_[row] = ps; ad_[row] = pd; }
            }
        }
    }
}

// ------- layer-2 aggregate: inline w, quarter-wave/edge, 2-in-flight --------
__global__ __launch_bounds__(256) void k_agg2(const unsigned short* __restrict__ h2b,
                                              const float* __restrict__ as,
                                              const float* __restrict__ ad,
                                              const int* __restrict__ off,
                                              const int* __restrict__ srcl,
                                              const float* __restrict__ b2,
                                              float* __restrict__ out, int N) {
    int wid = (blockIdx.x * blockDim.x + threadIdx.x) >> 6;
    int lane = threadIdx.x & 63;
    if (wid >= N) return;
    int p0 = off[wid], p1 = off[wid + 1];
    float adw = ad[wid];
    int g = lane >> 4, gl = lane & 15;
    float acc[4];
#pragma unroll
    for (int c = 0; c < 4; ++c) acc[c] = 0.f;
    float sumw = 0.f;
    for (int base = p0; base < p1; base += 64) {
        int p = base + lane;
        int cnt = min(64, p1 - base);
        int s = 0; float w = 0.f;
        if (p < p1) {
            s = srcl[p];
            float l = as[s] + adw;
            l = l >= 0.f ? l : NSLOPE * l;
            w = __expf(l);
        }
        int quads = (cnt + 3) >> 2;
        int jj = 0;
        for (; jj + 2 <= quads; jj += 2) {
            int e0 = 4 * jj + g, e1 = e0 + 4;
            int sa = __shfl(s, e0, 64), sb = __shfl(s, e1, 64);
            float wa = __shfl(w, e0, 64), wb = __shfl(w, e1, 64);
            u16x4 hva = *(const u16x4*)&h2b[(size_t)sa * 64 + gl * 4];
            u16x4 hvb = *(const u16x4*)&h2b[(size_t)sb * 64 + gl * 4];
            sumw += wa + wb;
            acc[0] += wa * bf16_to_f(hva.x) + wb * bf16_to_f(hvb.x);
            acc[1] += wa * bf16_to_f(hva.y) + wb * bf16_to_f(hvb.y);
            acc[2] += wa * bf16_to_f(hva.z) + wb * bf16_to_f(hvb.z);
            acc[3] += wa * bf16_to_f(hva.w) + wb * bf16_to_f(hvb.w);
        }
        for (; jj < quads; ++jj) {
            int e0 = 4 * jj + g;
            int sa = __shfl(s, e0, 64);
            float wa = __shfl(w, e0, 64);
            u16x4 hva = *(const u16x4*)&h2b[(size_t)sa * 64 + gl * 4];
            sumw += wa;
            acc[0] += wa * bf16_to_f(hva.x);
            acc[1] += wa * bf16_to_f(hva.y);
            acc[2] += wa * bf16_to_f(hva.z);
            acc[3] += wa * bf16_to_f(hva.w);
        }
    }
#pragma unroll
    for (int c = 0; c < 4; ++c) {
        acc[c] += __shfl_xor(acc[c], 16, 64);
        acc[c] += __shfl_xor(acc[c], 32, 64);
    }
    sumw += __shfl_xor(sumw, 16, 64);
    sumw += __shfl_xor(sumw, 32, 64);
    if (g == 0) {
        float inv = 1.0f / sumw;
        float4 bv = *(const float4*)&b2[gl * 4];
        float4 o;
        o.x = acc[0] * inv + bv.x;
        o.y = acc[1] * inv + bv.y;
        o.z = acc[2] * inv + bv.z;
        o.w = acc[3] * inv + bv.w;
        *(float4*)&out[(size_t)wid * 64 + gl * 4] = o;
    }
}

// ---------------- launch ----------------
extern "C" void kernel_launch(void* const* d_in, const int* in_sizes, int n_in,
                              void* d_out, int out_size, void* d_ws, size_t ws_size,
                              hipStream_t stream) {
    if (n_in < 10) return;
    const float* x   = (const float*)d_in[0];
    const int*   ei  = (const int*)d_in[1];
    const float* W1  = (const float*)d_in[2];
    const float* a1s = (const float*)d_in[3];
    const float* a1d = (const float*)d_in[4];
    const float* b1  = (const float*)d_in[5];
    const float* W2  = (const float*)d_in[6];
    const float* a2s = (const float*)d_in[7];
    const float* a2d = (const float*)d_in[8];
    const float* b2  = (const float*)d_in[9];
    float* out = (float*)d_out;

    const int N = in_sizes[0] / 256;
    const int E = in_sizes[1] / 2;
    const int T = E + N;
    const int* esrc = ei;
    const int* edst = ei + E;

    char* ws = (char*)d_ws;
    size_t o = 0;
    auto alloc = [&](size_t bytes) -> void* {
        void* p = ws + o;
        o = (o + bytes + 255) & ~(size_t)255;
        return p;
    };
    // Xhi (dead after gemm1) aliased with helu_b (written by agg1)
    size_t szX = (size_t)N * 256 * 2;
    char* regionA = (char*)alloc(szX);
    unsigned short* Xhi    = (unsigned short*)regionA;
    unsigned short* helu_b = (unsigned short*)regionA;

    unsigned short* h1b  = (unsigned short*)alloc((size_t)N * 256 * 2);
    unsigned short* W1hi = (unsigned short*)alloc(256 * 256 * 2);
    unsigned short* W1lo = (unsigned short*)alloc(256 * 256 * 2);
    unsigned short* W2hi = (unsigned short*)alloc(64 * 256 * 2);
    unsigned short* h2b  = (unsigned short*)alloc((size_t)N * 64 * 2);
    float* al1s = (float*)alloc((size_t)N * 2 * 4);
    float* al1d = (float*)alloc((size_t)N * 2 * 4);
    float* al2s = (float*)alloc((size_t)N * 4);
    float* al2d = (float*)alloc((size_t)N * 4);
    int* deg  = (int*)alloc((size_t)(N + 64) * 4);  // deg[N] + ticket counter
    int* ticket = deg + N;
    int* off  = (int*)alloc((size_t)(N + 1) * 4);
    int* cur  = (int*)alloc((size_t)N * 4);
    int* part = (int*)alloc(256 * 4);
    int* srcl = (int*)alloc((size_t)T * 4);
    if (o > ws_size) return;

    const int CH = (N + 255) / 256;
    const int total4 = N * 64;
    const int BX = (total4 + 255) / 256;
    const int BH = (E + 255) / 256;

    hipMemsetAsync(deg, 0, (size_t)(N + 64) * 4, stream);
    k_prep_all<<<BX + 128 + BH, 256, 0, stream>>>(x, W1, W2, edst, Xhi,
                                                  W1hi, W1lo, W2hi, deg,
                                                  BX, total4, E);
    k_scan_ab<<<256, 256, 0, stream>>>(deg, part, ticket, &off[N], N, CH);
    k_scan_c<<<256, 256, 0, stream>>>(deg, part, off, cur, srcl, N, CH);
    k_fill<<<(E + 255) / 256, 256, 0, stream>>>(esrc, edst, cur, srcl, E);

    // layer 1
    dim3 g1((N + 127) / 128, 2);
    k_gemm1<<<g1, 256, 0, stream>>>(Xhi, W1hi, W1lo, a1s, a1d, h1b, al1s, al1d, N);
    k_agg1<<<(N + 3) / 4, 256, 0, stream>>>(h1b, al1s, al1d, off, srcl, b1, helu_b, N);

    // layer 2
    k_gemm2<<<(N + 127) / 128, 256, 0, stream>>>(helu_b, W2hi, a2s, a2d,
                                                 h2b, al2s, al2d, N);
    k_agg2<<<(N + 3) / 4, 256, 0, stream>>>(h2b, al2s, al2d, off, srcl, b2, out, N);
}